// Round 8
// baseline (1421.052 us; speedup 1.0000x reference)
//
#include <hip/hip_runtime.h>

typedef unsigned short ushort_t;
typedef unsigned int uint32;

typedef __bf16 bf16x8 __attribute__((ext_vector_type(8)));
typedef float f32x4 __attribute__((ext_vector_type(4)));

#define DEVI static __device__ __forceinline__

constexpr int N_ = 50000;
constexpr int E_ = 800000;
constexpr int RN = 64;          // dst nodes per block in fused GNN kernels
constexpr int NB = (N_ + RN - 1) / RN;   // 782

// ---- workspace layout (bytes) ----
constexpr size_t OFF_XB   = 0;          // bf16 N*64   (dead after gnn1)
constexpr size_t OFF_SRC  = 6400000;    // int E unsorted (dead after scatter)
constexpr size_t OFF_DST  = 9600000;    // int E unsorted (dead after scatter)
constexpr size_t OFF_Y1   = 0;          // bf16 N*256 (mlp phase; aliases XB/SRC/DST)
constexpr size_t OFF_H    = 25600000;   // bf16 N*128 (dead after gnn2)
constexpr size_t OFF_ESRC = 38400000;   // int E sorted-by-dst src
constexpr size_t OFF_EDST = 41600000;   // int E sorted dst
constexpr size_t OFF_CUR  = 44800000;   // int N histogram/cursors (zeroed each launch)
constexpr size_t OFF_Y2   = 25600000;   // bf16 N*256 (mlp phase; aliases H/ESRC/EDST/CUR)
constexpr size_t OFF_G    = 51200000;   // bf16 N*64
constexpr size_t OFF_OFFA = 57600000;   // int N+1 prefix sums
constexpr size_t OFF_MODE = 57800064;   // int N
constexpr size_t OFF_WTH  = 58000064;   // bf16 16*256 head weights^T
constexpr size_t OFF_E16  = 58008256;   // bf16 emb 3*16 (pad)
constexpr size_t OFF_FLAG = 58008384;   // int32 x 4
constexpr size_t WS_NEED  = 58008400;

DEVI ushort_t f2b(float f){ union { float f; uint32 u; } x; x.f = f;
  uint32 r = (x.u + 0x7fffu + ((x.u >> 16) & 1u)) >> 16; return (ushort_t)r; }

DEVI bf16x8 cvt8(const float* p){
  f32x4 u = *(const f32x4*)p, v = *(const f32x4*)(p + 4);
  bf16x8 r;
#pragma unroll
  for (int j = 0; j < 4; ++j) r[j] = (__bf16)u[j];
#pragma unroll
  for (int j = 0; j < 4; ++j) r[4+j] = (__bf16)v[j];
  return r;
}

// ---- diagnostic ----
__global__ void k_code(float* out, float code){
  if (threadIdx.x == 0 && blockIdx.x == 0) out[0] = code;
}

// ---- detect int64 vs int32 layout (proven int32; kept as insurance) ----
__launch_bounds__(256)
__global__ void k_detect(const int* __restrict__ ei, const int* __restrict__ mo,
                         int* __restrict__ flags)
{
  __shared__ int red[2];
  if (threadIdx.x == 0) { red[0] = 0; red[1] = 0; }
  __syncthreads();
  int a = 0, b = 0;
  for (int i = threadIdx.x; i < 4096; i += 256) a |= ei[2*i + 1];
  for (int i = threadIdx.x; i < 2048; i += 256) b |= mo[2*i + 1];
  atomicOr(&red[0], a);
  atomicOr(&red[1], b);
  __syncthreads();
  if (threadIdx.x == 0) { flags[0] = (red[0] == 0) ? 1 : 0; flags[1] = (red[1] == 0) ? 1 : 0; }
}

// ---- normalize indices + histogram dst into CUR (CUR pre-zeroed) ----
__launch_bounds__(256)
__global__ void k_cvt(const int* __restrict__ ei, const int* __restrict__ mo,
                      const int* __restrict__ flags,
                      int* __restrict__ SRC, int* __restrict__ DST, int* __restrict__ MODE,
                      int* __restrict__ CUR)
{
  const int fE = flags[0], fM = flags[1];
  const int g = gridDim.x * 256;
  for (int e = blockIdx.x*256 + threadIdx.x; e < E_; e += g) {
    int s = fE ? ei[2*e]        : ei[e];
    int d = fE ? ei[2*E_ + 2*e] : ei[E_ + e];
    SRC[e] = s; DST[e] = d;
    atomicAdd(&CUR[d], 1);
  }
  for (int n = blockIdx.x*256 + threadIdx.x; n < N_; n += g) {
    MODE[n] = fM ? mo[2*n] : mo[n];
  }
}

// ---- single-block exclusive scan: CUR(deg) -> OFFA[0..N], reset CUR=OFFA prefix ----
__launch_bounds__(1024)
__global__ void k_scan(int* __restrict__ CUR, int* __restrict__ OFFA)
{
  __shared__ int ls[1024];
  const int t = threadIdx.x;
  const int CH = 49;                       // 1024*49 = 50176 >= 50000
  const int start = t * CH;
  const int end = min(start + CH, N_);
  int s = 0;
  for (int i = start; i < end; ++i) s += CUR[i];
  ls[t] = s;
  __syncthreads();
#pragma unroll
  for (int off = 1; off < 1024; off <<= 1) {
    int v = (t >= off) ? ls[t - off] : 0;
    __syncthreads();
    ls[t] += v;
    __syncthreads();
  }
  int run = (t == 0) ? 0 : ls[t - 1];
  for (int i = start; i < end; ++i) {
    int d = CUR[i];
    OFFA[i] = run;
    CUR[i]  = run;
    run += d;
  }
  if (t == 1023) OFFA[N_] = ls[1023];
}

// ---- scatter edges into dst-sorted order ----
__launch_bounds__(256)
__global__ void k_scatter(const int* __restrict__ SRC, const int* __restrict__ DST,
                          int* __restrict__ CUR,
                          int* __restrict__ ESRC, int* __restrict__ EDST)
{
  const int g = gridDim.x * 256;
  for (int e = blockIdx.x*256 + threadIdx.x; e < E_; e += g) {
    int d = DST[e];
    int pos = atomicAdd(&CUR[d], 1);
    ESRC[pos] = SRC[e];
    EDST[pos] = d;
  }
}

// ---- prep: x_nodes f32->bf16, head W^T bf16, emb bf16 ----
__launch_bounds__(256)
__global__ void k_prep(const float* __restrict__ xn, const float* __restrict__ wm,
                       const float* __restrict__ wsw, const float* __restrict__ emb,
                       ushort_t* __restrict__ xb, ushort_t* __restrict__ wth,
                       ushort_t* __restrict__ e16)
{
  int i = blockIdx.x * 256 + threadIdx.x;
  if (i < N_*64) {
    xb[i] = f2b(xn[i]);
  } else if (i < N_*64 + 4096) {
    int j = i - N_*64; int n = j >> 8, k = j & 255;
    wth[j] = f2b(n < 8 ? wm[k*8 + n] : wsw[k*8 + (n - 8)]);
  } else if (i < N_*64 + 4096 + 48) {
    int j = i - (N_*64 + 4096);
    e16[j] = f2b(emb[j]);
  }
}

// ==== fused GNN layer 1: per-block dst range, LDS accumulation, fused node MLP ====
// edge: t = relu(cat[x_dst,x_src]@W1a + b1a)  -> accL (LDS atomics)
// node: h = relu((accL/deg)@W1b + b1b), 0 if deg==0  -> H bf16
__launch_bounds__(256)
__global__ void k_gnn1(const ushort_t* __restrict__ XB,
                       const int* __restrict__ ESRC, const int* __restrict__ EDST,
                       const int* __restrict__ OFFA,
                       const float* __restrict__ w1a, const float* __restrict__ b1a,
                       const float* __restrict__ w1b, const float* __restrict__ b1b,
                       ushort_t* __restrict__ H)
{
  __shared__ __attribute__((aligned(16))) char U[34816 + 34816];
  ushort_t* Wt   = (ushort_t*)U;            // 128x136 W1a^T (transient)
  float*    accL = (float*)U;               // 64 rows x 132 stride = 33792 B (reuses Wt)
  ushort_t* Wbt  = (ushort_t*)(U + 34816);  // 128x136 W1b^T (persistent)

  const int tid = threadIdx.x;
  for (int i = tid; i < 128*128; i += 256) {
    int k = i >> 7, n = i & 127;
    Wt[n*136 + k]  = f2b(w1a[i]);
    Wbt[n*136 + k] = f2b(w1b[i]);
  }
  __syncthreads();
  const int wave = tid >> 6, lane = tid & 63;
  const int p = lane & 15, q = lane >> 4;
  bf16x8 bfr[8][4];
#pragma unroll
  for (int nt = 0; nt < 8; ++nt)
#pragma unroll
    for (int s = 0; s < 4; ++s)
      bfr[nt][s] = *(const bf16x8*)&Wt[(nt*16 + p)*136 + s*32 + q*8];
  float biasA[8], biasB[8];
#pragma unroll
  for (int nt = 0; nt < 8; ++nt) { biasA[nt] = b1a[nt*16 + p]; biasB[nt] = b1b[nt*16 + p]; }
  __syncthreads();                          // all Wt reads done
  for (int i = tid; i < 64*132; i += 256) accL[i] = 0.0f;
  __syncthreads();

  const int n0 = blockIdx.x * RN;
  const int nEnd = min(n0 + RN, N_);
  const int off0 = OFFA[n0], off1 = OFFA[nEnd];
  const int ntiles = (off1 - off0 + 15) >> 4;

  for (int t = wave; t < ntiles; t += 4) {
    const int e_p = off0 + (t << 4) + p;
    const bool valid = e_p < off1;
    const int sidx = valid ? ESRC[e_p] : 0;
    const int dl   = valid ? (EDST[e_p] - n0) : -1;
    const int dn   = valid ? (n0 + dl) : 0;
    const ushort_t* xd = XB + (size_t)dn * 64;
    const ushort_t* xs = XB + (size_t)sidx * 64;
    bf16x8 afr[4];
    afr[0] = *(const bf16x8*)(xd + q*8);
    afr[1] = *(const bf16x8*)(xd + 32 + q*8);
    afr[2] = *(const bf16x8*)(xs + q*8);
    afr[3] = *(const bf16x8*)(xs + 32 + q*8);
    f32x4 acc[8];
#pragma unroll
    for (int nt = 0; nt < 8; ++nt) acc[nt] = (f32x4){0.f,0.f,0.f,0.f};
#pragma unroll
    for (int nt = 0; nt < 8; ++nt)
#pragma unroll
      for (int s = 0; s < 4; ++s)
        acc[nt] = __builtin_amdgcn_mfma_f32_16x16x32_bf16(afr[s], bfr[nt][s], acc[nt], 0, 0, 0);
    int dlr[4];
#pragma unroll
    for (int r = 0; r < 4; ++r) dlr[r] = __shfl(dl, q*4 + r);
#pragma unroll
    for (int nt = 0; nt < 8; ++nt)
#pragma unroll
      for (int r = 0; r < 4; ++r)
        if (dlr[r] >= 0)
          atomicAdd(&accL[dlr[r]*132 + nt*16 + p], fmaxf(acc[nt][r] + biasA[nt], 0.0f));
  }
  __syncthreads();

  // node MLP: wave handles 16 local rows [wave*16, wave*16+16)
  const int mrow = wave*16 + p;
  const int node = n0 + mrow;
  int deg = 0;
  if (node < N_) deg = OFFA[node + 1] - OFFA[node];
  const float inv = (deg > 0) ? 1.0f / (float)deg : 0.0f;
  bf16x8 a2[4];
#pragma unroll
  for (int s = 0; s < 4; ++s) {
    const float* sp = &accL[mrow*132 + s*32 + q*8];
    bf16x8 v;
#pragma unroll
    for (int j = 0; j < 8; ++j) v[j] = (__bf16)(sp[j] * inv);
    a2[s] = v;
  }
  f32x4 c2[8];
#pragma unroll
  for (int nt = 0; nt < 8; ++nt) c2[nt] = (f32x4){0.f,0.f,0.f,0.f};
#pragma unroll
  for (int nt = 0; nt < 8; ++nt)
#pragma unroll
    for (int s = 0; s < 4; ++s) {
      bf16x8 b = *(const bf16x8*)&Wbt[(nt*16 + p)*136 + s*32 + q*8];
      c2[nt] = __builtin_amdgcn_mfma_f32_16x16x32_bf16(a2[s], b, c2[nt], 0, 0, 0);
    }
  int degq[4];
#pragma unroll
  for (int r = 0; r < 4; ++r) degq[r] = __shfl(deg, q*4 + r);
#pragma unroll
  for (int nt = 0; nt < 8; ++nt)
#pragma unroll
    for (int r = 0; r < 4; ++r) {
      int orow = n0 + wave*16 + q*4 + r;
      if (orow < N_) {
        float v = (degq[r] > 0) ? fmaxf(c2[nt][r] + biasB[nt], 0.0f) : 0.0f;
        H[(size_t)orow*128 + nt*16 + p] = f2b(v);
      }
    }
}

// ==== fused GNN layer 2 ====
// edge: t2 = relu(cat[h_dst,h_src]@W2a + b2a) -> accL2 (LDS atomics)
// node: g = (accL2/deg)@W2b + b2b (no relu), 0 if deg==0 -> G bf16
__launch_bounds__(256)
__global__ void k_gnn2(const ushort_t* __restrict__ H,
                       const int* __restrict__ ESRC, const int* __restrict__ EDST,
                       const int* __restrict__ OFFA,
                       const float* __restrict__ w2a, const float* __restrict__ b2a,
                       const float* __restrict__ w2b, const float* __restrict__ b2b,
                       ushort_t* __restrict__ G)
{
  __shared__ __attribute__((aligned(16))) char U[33792 + 9216];
  ushort_t* Wt   = (ushort_t*)U;            // 64x264 W2a^T (transient)
  float*    accL = (float*)U;               // 64 rows x 68 stride = 17408 B (reuses Wt)
  ushort_t* Wbt  = (ushort_t*)(U + 33792);  // 64x72 W2b^T (persistent)

  const int tid = threadIdx.x;
  for (int i = tid; i < 256*64; i += 256) { int k = i >> 6, n = i & 63; Wt[n*264 + k]  = f2b(w2a[i]); }
  for (int i = tid; i < 64*64;  i += 256) { int k = i >> 6, n = i & 63; Wbt[n*72 + k] = f2b(w2b[i]); }
  __syncthreads();
  const int wave = tid >> 6, lane = tid & 63;
  const int p = lane & 15, q = lane >> 4;
  bf16x8 bfr[4][8];
#pragma unroll
  for (int nt = 0; nt < 4; ++nt)
#pragma unroll
    for (int s = 0; s < 8; ++s)
      bfr[nt][s] = *(const bf16x8*)&Wt[(nt*16 + p)*264 + s*32 + q*8];
  float biasA[4], biasB[4];
#pragma unroll
  for (int nt = 0; nt < 4; ++nt) { biasA[nt] = b2a[nt*16 + p]; biasB[nt] = b2b[nt*16 + p]; }
  __syncthreads();
  for (int i = tid; i < 64*68; i += 256) accL[i] = 0.0f;
  __syncthreads();

  const int n0 = blockIdx.x * RN;
  const int nEnd = min(n0 + RN, N_);
  const int off0 = OFFA[n0], off1 = OFFA[nEnd];
  const int ntiles = (off1 - off0 + 15) >> 4;

  for (int t = wave; t < ntiles; t += 4) {
    const int e_p = off0 + (t << 4) + p;
    const bool valid = e_p < off1;
    const int sidx = valid ? ESRC[e_p] : 0;
    const int dl   = valid ? (EDST[e_p] - n0) : -1;
    const int dn   = valid ? (n0 + dl) : 0;
    const ushort_t* hd = H + (size_t)dn * 128;
    const ushort_t* hs = H + (size_t)sidx * 128;
    bf16x8 afr[8];
#pragma unroll
    for (int s = 0; s < 4; ++s) afr[s]     = *(const bf16x8*)(hd + s*32 + q*8);
#pragma unroll
    for (int s = 0; s < 4; ++s) afr[4 + s] = *(const bf16x8*)(hs + s*32 + q*8);
    f32x4 acc[4];
#pragma unroll
    for (int nt = 0; nt < 4; ++nt) acc[nt] = (f32x4){0.f,0.f,0.f,0.f};
#pragma unroll
    for (int nt = 0; nt < 4; ++nt)
#pragma unroll
      for (int s = 0; s < 8; ++s)
        acc[nt] = __builtin_amdgcn_mfma_f32_16x16x32_bf16(afr[s], bfr[nt][s], acc[nt], 0, 0, 0);
    int dlr[4];
#pragma unroll
    for (int r = 0; r < 4; ++r) dlr[r] = __shfl(dl, q*4 + r);
#pragma unroll
    for (int nt = 0; nt < 4; ++nt)
#pragma unroll
      for (int r = 0; r < 4; ++r)
        if (dlr[r] >= 0)
          atomicAdd(&accL[dlr[r]*68 + nt*16 + p], fmaxf(acc[nt][r] + biasA[nt], 0.0f));
  }
  __syncthreads();

  const int mrow = wave*16 + p;
  const int node = n0 + mrow;
  int deg = 0;
  if (node < N_) deg = OFFA[node + 1] - OFFA[node];
  const float inv = (deg > 0) ? 1.0f / (float)deg : 0.0f;
  bf16x8 a2[2];
#pragma unroll
  for (int s = 0; s < 2; ++s) {
    const float* sp = &accL[mrow*68 + s*32 + q*8];
    bf16x8 v;
#pragma unroll
    for (int j = 0; j < 8; ++j) v[j] = (__bf16)(sp[j] * inv);
    a2[s] = v;
  }
  f32x4 c2[4];
#pragma unroll
  for (int nt = 0; nt < 4; ++nt) c2[nt] = (f32x4){0.f,0.f,0.f,0.f};
#pragma unroll
  for (int nt = 0; nt < 4; ++nt)
#pragma unroll
    for (int s = 0; s < 2; ++s) {
      bf16x8 b = *(const bf16x8*)&Wbt[(nt*16 + p)*72 + s*32 + q*8];
      c2[nt] = __builtin_amdgcn_mfma_f32_16x16x32_bf16(a2[s], b, c2[nt], 0, 0, 0);
    }
  int degq[4];
#pragma unroll
  for (int r = 0; r < 4; ++r) degq[r] = __shfl(deg, q*4 + r);
#pragma unroll
  for (int nt = 0; nt < 4; ++nt)
#pragma unroll
    for (int r = 0; r < 4; ++r) {
      int orow = n0 + wave*16 + q*4 + r;
      if (orow < N_) {
        float v = (degq[r] > 0) ? (c2[nt][r] + biasB[nt]) : 0.0f;
        G[(size_t)orow*64 + nt*16 + p] = f2b(v);
      }
    }
}

// ---------------- mlp1 (MFMA): y1 = relu([state,g,me] @ W1 + b1); half-column blocks ----
__launch_bounds__(256)
__global__ void k_mlp1(const float* __restrict__ state, const ushort_t* __restrict__ gbuf,
                       const ushort_t* __restrict__ e16, const int* __restrict__ MODE,
                       const float* __restrict__ b1f, const float* __restrict__ w1,
                       ushort_t* __restrict__ y1)
{
  __shared__ __attribute__((aligned(16))) ushort_t Wt[128*168];
  const int tid = threadIdx.x;
  const int cb = (blockIdx.x & 1) * 128;
  for (int i = tid; i < 128*160; i += 256) {
    int n = i / 160, k = i - n*160;
    Wt[n*168 + k] = (k < 144) ? f2b(w1[k*256 + cb + n]) : (ushort_t)0;
  }
  __syncthreads();
  const int wave = tid >> 6, lane = tid & 63;
  const int p = lane & 15, q = lane >> 4;
  float bias[8];
#pragma unroll
  for (int nt = 0; nt < 8; ++nt) bias[nt] = b1f[cb + nt*16 + p];
  bf16x8 zed;
#pragma unroll
  for (int j = 0; j < 8; ++j) zed[j] = (__bf16)0.0f;
  const int nwaves = (gridDim.x >> 1) * 4;
  for (int t = (blockIdx.x >> 1)*4 + wave; t < N_/16; t += nwaves) {
    const int base = t * 16;
    const int node = base + p;
    bf16x8 afr[5];
    afr[0] = cvt8(state + (size_t)node*64 + q*8);
    afr[1] = cvt8(state + (size_t)node*64 + 32 + q*8);
    afr[2] = *(const bf16x8*)(gbuf + (size_t)node*64 + q*8);
    afr[3] = *(const bf16x8*)(gbuf + (size_t)node*64 + 32 + q*8);
    afr[4] = (q < 2) ? *(const bf16x8*)(e16 + (size_t)MODE[node]*16 + q*8) : zed;
    f32x4 acc[8];
#pragma unroll
    for (int nt = 0; nt < 8; ++nt) acc[nt] = (f32x4){0.f,0.f,0.f,0.f};
#pragma unroll
    for (int nt = 0; nt < 8; ++nt)
#pragma unroll
      for (int s = 0; s < 5; ++s) {
        bf16x8 b = *(const bf16x8*)&Wt[(nt*16 + p)*168 + s*32 + q*8];
        acc[nt] = __builtin_amdgcn_mfma_f32_16x16x32_bf16(afr[s], b, acc[nt], 0, 0, 0);
      }
#pragma unroll
    for (int nt = 0; nt < 8; ++nt)
#pragma unroll
      for (int r = 0; r < 4; ++r) {
        float v = fmaxf(acc[nt][r] + bias[nt], 0.0f);
        y1[(size_t)(base + q*4 + r)*256 + cb + nt*16 + p] = f2b(v);
      }
  }
}

// ---------------- mlp2 (MFMA): y2 = relu(y1 @ W2 + b2); half-column blocks ----
__launch_bounds__(256)
__global__ void k_mlp2(const ushort_t* __restrict__ y1, const float* __restrict__ w2,
                       const float* __restrict__ b2f, ushort_t* __restrict__ y2)
{
  __shared__ __attribute__((aligned(16))) ushort_t Wt[128*264];
  const int tid = threadIdx.x;
  const int cb = (blockIdx.x & 1) * 128;
  for (int i = tid; i < 128*256; i += 256) {
    int n = i >> 8, k = i & 255;
    Wt[n*264 + k] = f2b(w2[k*256 + cb + n]);
  }
  __syncthreads();
  const int wave = tid >> 6, lane = tid & 63;
  const int p = lane & 15, q = lane >> 4;
  float bias[8];
#pragma unroll
  for (int nt = 0; nt < 8; ++nt) bias[nt] = b2f[cb + nt*16 + p];
  const int nwaves = (gridDim.x >> 1) * 4;
  for (int t = (blockIdx.x >> 1)*4 + wave; t < N_/16; t += nwaves) {
    const int base = t * 16;
    bf16x8 afr[8];
#pragma unroll
    for (int s = 0; s < 8; ++s)
      afr[s] = *(const bf16x8*)(y1 + (size_t)(base + p)*256 + s*32 + q*8);
    f32x4 acc[8];
#pragma unroll
    for (int nt = 0; nt < 8; ++nt) acc[nt] = (f32x4){0.f,0.f,0.f,0.f};
#pragma unroll
    for (int nt = 0; nt < 8; ++nt)
#pragma unroll
      for (int s = 0; s < 8; ++s) {
        bf16x8 b = *(const bf16x8*)&Wt[(nt*16 + p)*264 + s*32 + q*8];
        acc[nt] = __builtin_amdgcn_mfma_f32_16x16x32_bf16(afr[s], b, acc[nt], 0, 0, 0);
      }
#pragma unroll
    for (int nt = 0; nt < 8; ++nt)
#pragma unroll
      for (int r = 0; r < 4; ++r) {
        float v = fmaxf(acc[nt][r] + bias[nt], 0.0f);
        y2[(size_t)(base + q*4 + r)*256 + cb + nt*16 + p] = f2b(v);
      }
  }
}

// ---------------- heads (MFMA): f32 out ----
__launch_bounds__(256)
__global__ void k_heads(const ushort_t* __restrict__ y2, const ushort_t* __restrict__ wth,
                        const float* __restrict__ bm, const float* __restrict__ bs,
                        float* __restrict__ out)
{
  const int tid = threadIdx.x;
  const int wave = tid >> 6, lane = tid & 63;
  const int p = lane & 15, q = lane >> 4;
  bf16x8 bfr[8];
#pragma unroll
  for (int s = 0; s < 8; ++s)
    bfr[s] = *(const bf16x8*)(wth + (size_t)p*256 + s*32 + q*8);
  float bias = (p < 8) ? bm[p] : bs[p - 8];
  const int nwaves = gridDim.x * 4;
  for (int t = blockIdx.x*4 + wave; t < N_/16; t += nwaves) {
    const int base = t * 16;
    f32x4 acc = (f32x4){0.f,0.f,0.f,0.f};
#pragma unroll
    for (int s = 0; s < 8; ++s) {
      bf16x8 a = *(const bf16x8*)(y2 + (size_t)(base + p)*256 + s*32 + q*8);
      acc = __builtin_amdgcn_mfma_f32_16x16x32_bf16(a, bfr[s], acc, 0, 0, 0);
    }
#pragma unroll
    for (int r = 0; r < 4; ++r) {
      int node = base + q*4 + r;
      float v = acc[r] + bias;
      if (p < 8) {
        out[(size_t)node*8 + p] = v;
      } else {
        v = fminf(fmaxf(v, -20.f), 2.f);
        out[(size_t)N_*8 + (size_t)node*8 + (p - 8)] = v;
      }
    }
  }
}

extern "C" void kernel_launch(void* const* d_in, const int* in_sizes, int n_in,
                              void* d_out, int out_size, void* d_ws, size_t ws_size,
                              hipStream_t stream)
{
  float* out = (float*)d_out;

  float code = 0.0f;
  if      (n_in != 21)                 code = 1.0e6f;
  else if (in_sizes[0]  != 3200000)    code = 2.0e6f;
  else if (in_sizes[1]  != 3200000)    code = 3.0e6f;
  else if (in_sizes[2]  != 1600000)    code = 4.0e6f;
  else if (in_sizes[3]  != 50000)      code = 5.0e6f;
  else if (in_sizes[4]  != 16384)      code = 6.0e6f;
  else if (in_sizes[13] != 36864)      code = 7.0e6f;
  else if (in_sizes[15] != 65536)      code = 8.0e6f;
  else if (in_sizes[17] != 2048)       code = 9.0e6f;
  else if (out_size     != 800000)     code = 1.0e7f;
  else if (ws_size      < WS_NEED)     code = 1.1e7f;
  if (code != 0.0f) {
    k_code<<<1, 64, 0, stream>>>(out, code);
    return;
  }

  const float* state = (const float*)d_in[0];
  const float* xn    = (const float*)d_in[1];
  const int*   ei    = (const int*)d_in[2];
  const int*   mo    = (const int*)d_in[3];
  const float* w1a   = (const float*)d_in[4];
  const float* b1a   = (const float*)d_in[5];
  const float* w1b   = (const float*)d_in[6];
  const float* b1b   = (const float*)d_in[7];
  const float* w2a   = (const float*)d_in[8];
  const float* b2a   = (const float*)d_in[9];
  const float* w2b   = (const float*)d_in[10];
  const float* b2b   = (const float*)d_in[11];
  const float* emb   = (const float*)d_in[12];
  const float* w1    = (const float*)d_in[13];
  const float* b1    = (const float*)d_in[14];
  const float* w2    = (const float*)d_in[15];
  const float* b2    = (const float*)d_in[16];
  const float* wm    = (const float*)d_in[17];
  const float* bm    = (const float*)d_in[18];
  const float* wsw   = (const float*)d_in[19];
  const float* bs    = (const float*)d_in[20];

  char* ws = (char*)d_ws;
  ushort_t* XB   = (ushort_t*)(ws + OFF_XB);
  int*      SRC  = (int*)(ws + OFF_SRC);
  int*      DST  = (int*)(ws + OFF_DST);
  ushort_t* H    = (ushort_t*)(ws + OFF_H);
  int*      ESRC = (int*)(ws + OFF_ESRC);
  int*      EDST = (int*)(ws + OFF_EDST);
  int*      CUR  = (int*)(ws + OFF_CUR);
  ushort_t* G    = (ushort_t*)(ws + OFF_G);
  int*      OFFA = (int*)(ws + OFF_OFFA);
  int*      MODE = (int*)(ws + OFF_MODE);
  ushort_t* WTH  = (ushort_t*)(ws + OFF_WTH);
  ushort_t* E16  = (ushort_t*)(ws + OFF_E16);
  int*      FLG  = (int*)(ws + OFF_FLAG);
  ushort_t* Y1   = (ushort_t*)(ws + OFF_Y1);
  ushort_t* Y2   = (ushort_t*)(ws + OFF_Y2);

  hipMemsetAsync(CUR, 0, (size_t)N_ * 4, stream);
  k_detect <<<1,    256,  0, stream>>>(ei, mo, FLG);
  k_cvt    <<<1600, 256,  0, stream>>>(ei, mo, FLG, SRC, DST, MODE, CUR);
  k_scan   <<<1,    1024, 0, stream>>>(CUR, OFFA);
  k_scatter<<<1600, 256,  0, stream>>>(SRC, DST, CUR, ESRC, EDST);
  k_prep   <<<12517,256,  0, stream>>>(xn, wm, wsw, emb, XB, WTH, E16);
  k_gnn1   <<<NB,   256,  0, stream>>>(XB, ESRC, EDST, OFFA, w1a, b1a, w1b, b1b, H);
  k_gnn2   <<<NB,   256,  0, stream>>>(H, ESRC, EDST, OFFA, w2a, b2a, w2b, b2b, G);
  k_mlp1   <<<256,  256,  0, stream>>>(state, G, E16, MODE, b1, w1, Y1);
  k_mlp2   <<<256,  256,  0, stream>>>(Y1, w2, b2, Y2);
  k_heads  <<<128,  256,  0, stream>>>(Y2, WTH, bm, bs, out);
}

// Round 9
// 593.753 us; speedup vs baseline: 2.3933x; 2.3933x over previous
//
#include <hip/hip_runtime.h>

typedef unsigned short ushort_t;
typedef unsigned int uint32;

typedef __bf16 bf16x8 __attribute__((ext_vector_type(8)));
typedef float f32x4 __attribute__((ext_vector_type(4)));

#define DEVI static __device__ __forceinline__

constexpr int N_ = 50000;
constexpr int E_ = 800000;
constexpr int RN = 64;                    // dst nodes per block in fused GNN kernels
constexpr int NB = (N_ + RN - 1) / RN;    // 782

// ---- workspace layout (bytes) ----
constexpr size_t OFF_XB   = 0;          // bf16 N*64   (dead after gnn1)
constexpr size_t OFF_SRC  = 6400000;    // int E unsorted (dead after scatter)
constexpr size_t OFF_DST  = 9600000;    // int E unsorted (dead after scatter)
constexpr size_t OFF_Y1   = 0;          // bf16 N*256 (mlp phase; aliases XB/SRC/DST)
constexpr size_t OFF_H    = 25600000;   // bf16 N*128 (dead after gnn2)
constexpr size_t OFF_ESRC = 38400000;   // int E sorted-by-dst src
constexpr size_t OFF_CUR  = 44800000;   // int N histogram/cursors (zeroed each launch)
constexpr size_t OFF_Y2   = 25600000;   // bf16 N*256 (mlp phase; aliases H/ESRC/CUR)
constexpr size_t OFF_G    = 51200000;   // bf16 N*64
constexpr size_t OFF_OFFA = 57600000;   // int N+1 prefix sums
constexpr size_t OFF_MODE = 57800064;   // int N
constexpr size_t OFF_WTH  = 58000064;   // bf16 16*256 head weights^T
constexpr size_t OFF_E16  = 58008256;   // bf16 emb 3*16 (pad)
constexpr size_t OFF_FLAG = 58008384;   // int32 x 4
constexpr size_t WS_NEED  = 58008400;

DEVI ushort_t f2b(float f){ union { float f; uint32 u; } x; x.f = f;
  uint32 r = (x.u + 0x7fffu + ((x.u >> 16) & 1u)) >> 16; return (ushort_t)r; }

DEVI bf16x8 cvt8(const float* p){
  f32x4 u = *(const f32x4*)p, v = *(const f32x4*)(p + 4);
  bf16x8 r;
#pragma unroll
  for (int j = 0; j < 4; ++j) r[j] = (__bf16)u[j];
#pragma unroll
  for (int j = 0; j < 4; ++j) r[4+j] = (__bf16)v[j];
  return r;
}

// ---- diagnostic ----
__global__ void k_code(float* out, float code){
  if (threadIdx.x == 0 && blockIdx.x == 0) out[0] = code;
}

// ---- detect int64 vs int32 layout (proven int32; kept as insurance) ----
__launch_bounds__(256)
__global__ void k_detect(const int* __restrict__ ei, const int* __restrict__ mo,
                         int* __restrict__ flags)
{
  __shared__ int red[2];
  if (threadIdx.x == 0) { red[0] = 0; red[1] = 0; }
  __syncthreads();
  int a = 0, b = 0;
  for (int i = threadIdx.x; i < 4096; i += 256) a |= ei[2*i + 1];
  for (int i = threadIdx.x; i < 2048; i += 256) b |= mo[2*i + 1];
  atomicOr(&red[0], a);
  atomicOr(&red[1], b);
  __syncthreads();
  if (threadIdx.x == 0) { flags[0] = (red[0] == 0) ? 1 : 0; flags[1] = (red[1] == 0) ? 1 : 0; }
}

// ---- normalize indices + histogram dst into CUR (CUR pre-zeroed); int atomics = native ----
__launch_bounds__(256)
__global__ void k_cvt(const int* __restrict__ ei, const int* __restrict__ mo,
                      const int* __restrict__ flags,
                      int* __restrict__ SRC, int* __restrict__ DST, int* __restrict__ MODE,
                      int* __restrict__ CUR)
{
  const int fE = flags[0], fM = flags[1];
  const int g = gridDim.x * 256;
  for (int e = blockIdx.x*256 + threadIdx.x; e < E_; e += g) {
    int s = fE ? ei[2*e]        : ei[e];
    int d = fE ? ei[2*E_ + 2*e] : ei[E_ + e];
    SRC[e] = s; DST[e] = d;
    atomicAdd(&CUR[d], 1);
  }
  for (int n = blockIdx.x*256 + threadIdx.x; n < N_; n += g) {
    MODE[n] = fM ? mo[2*n] : mo[n];
  }
}

// ---- single-block exclusive scan: CUR(deg) -> OFFA[0..N], reset CUR=prefix ----
__launch_bounds__(1024)
__global__ void k_scan(int* __restrict__ CUR, int* __restrict__ OFFA)
{
  __shared__ int ls[1024];
  const int t = threadIdx.x;
  const int CH = 49;
  const int start = t * CH;
  const int end = min(start + CH, N_);
  int s = 0;
  for (int i = start; i < end; ++i) s += CUR[i];
  ls[t] = s;
  __syncthreads();
#pragma unroll
  for (int off = 1; off < 1024; off <<= 1) {
    int v = (t >= off) ? ls[t - off] : 0;
    __syncthreads();
    ls[t] += v;
    __syncthreads();
  }
  int run = (t == 0) ? 0 : ls[t - 1];
  for (int i = start; i < end; ++i) {
    int d = CUR[i];
    OFFA[i] = run;
    CUR[i]  = run;
    run += d;
  }
  if (t == 1023) OFFA[N_] = ls[1023];
}

// ---- scatter edge srcs into dst-sorted order ----
__launch_bounds__(256)
__global__ void k_scatter(const int* __restrict__ SRC, const int* __restrict__ DST,
                          int* __restrict__ CUR, int* __restrict__ ESRC)
{
  const int g = gridDim.x * 256;
  for (int e = blockIdx.x*256 + threadIdx.x; e < E_; e += g) {
    int d = DST[e];
    int pos = atomicAdd(&CUR[d], 1);
    ESRC[pos] = SRC[e];
  }
}

// ---- prep: x_nodes f32->bf16, head W^T bf16, emb bf16 ----
__launch_bounds__(256)
__global__ void k_prep(const float* __restrict__ xn, const float* __restrict__ wm,
                       const float* __restrict__ wsw, const float* __restrict__ emb,
                       ushort_t* __restrict__ xb, ushort_t* __restrict__ wth,
                       ushort_t* __restrict__ e16)
{
  int i = blockIdx.x * 256 + threadIdx.x;
  if (i < N_*64) {
    xb[i] = f2b(xn[i]);
  } else if (i < N_*64 + 4096) {
    int j = i - N_*64; int n = j >> 8, k = j & 255;
    wth[j] = f2b(n < 8 ? wm[k*8 + n] : wsw[k*8 + (n - 8)]);
  } else if (i < N_*64 + 4096 + 48) {
    int j = i - (N_*64 + 4096);
    e16[j] = f2b(emb[j]);
  }
}

// ==== fused GNN layer 1, atomic-free ====
// wave owns 16 dst nodes + their contiguous sorted edges; per-tile MFMA -> masked relu ->
// in-register row reduction (in-lane + shfl_xor) -> per-node reg sums -> mean to LDS ->
// restage W1b -> per-wave MFMA node MLP -> H
__launch_bounds__(256)
__global__ void k_gnn1(const ushort_t* __restrict__ XB,
                       const int* __restrict__ ESRC, const int* __restrict__ OFFA,
                       const float* __restrict__ w1a, const float* __restrict__ b1a,
                       const float* __restrict__ w1b, const float* __restrict__ b1b,
                       ushort_t* __restrict__ H)
{
  __shared__ __attribute__((aligned(16))) ushort_t WS[128*136];   // Wa^T then Wb^T
  __shared__ __attribute__((aligned(16))) ushort_t MEAN[64*136];  // 64 nodes x 128ch bf16
  const int tid = threadIdx.x;
  for (int i = tid; i < 128*128; i += 256) { int k = i >> 7, n = i & 127; WS[n*136 + k] = f2b(w1a[i]); }
  __syncthreads();
  const int wave = tid >> 6, lane = tid & 63;
  const int p = lane & 15, q = lane >> 4;
  bf16x8 bfr[8][4];
#pragma unroll
  for (int nt = 0; nt < 8; ++nt)
#pragma unroll
    for (int s = 0; s < 4; ++s)
      bfr[nt][s] = *(const bf16x8*)&WS[(nt*16 + p)*136 + s*32 + q*8];
  float biasA[8];
#pragma unroll
  for (int nt = 0; nt < 8; ++nt) biasA[nt] = b1a[nt*16 + p];
  const int n0 = blockIdx.x * RN;

  for (int m = 0; m < 16; ++m) {
    const int node = n0 + wave*16 + m;
    int eb = 0, deg = 0;
    if (node < N_) { eb = OFFA[node]; deg = OFFA[node + 1] - eb; }
    const int nodeC = min(node, N_ - 1);
    const ushort_t* xd = XB + (size_t)nodeC * 64;
    bf16x8 ad0 = *(const bf16x8*)(xd + q*8);
    bf16x8 ad1 = *(const bf16x8*)(xd + 32 + q*8);
    float sr[8];
#pragma unroll
    for (int nt = 0; nt < 8; ++nt) sr[nt] = 0.0f;
    for (int t = 0; t*16 < deg; ++t) {
      const int e = eb + t*16 + p;
      const int src = (t*16 + p < deg) ? ESRC[e] : nodeC;
      const ushort_t* xs = XB + (size_t)src * 64;
      bf16x8 as0 = *(const bf16x8*)(xs + q*8);
      bf16x8 as1 = *(const bf16x8*)(xs + 32 + q*8);
      f32x4 acc[8];
#pragma unroll
      for (int nt = 0; nt < 8; ++nt) acc[nt] = (f32x4){0.f,0.f,0.f,0.f};
#pragma unroll
      for (int nt = 0; nt < 8; ++nt) {
        acc[nt] = __builtin_amdgcn_mfma_f32_16x16x32_bf16(ad0, bfr[nt][0], acc[nt], 0, 0, 0);
        acc[nt] = __builtin_amdgcn_mfma_f32_16x16x32_bf16(ad1, bfr[nt][1], acc[nt], 0, 0, 0);
        acc[nt] = __builtin_amdgcn_mfma_f32_16x16x32_bf16(as0, bfr[nt][2], acc[nt], 0, 0, 0);
        acc[nt] = __builtin_amdgcn_mfma_f32_16x16x32_bf16(as1, bfr[nt][3], acc[nt], 0, 0, 0);
      }
      const int base = t*16 + q*4;
#pragma unroll
      for (int nt = 0; nt < 8; ++nt) {
        float vs = 0.0f;
#pragma unroll
        for (int r = 0; r < 4; ++r)
          vs += (base + r < deg) ? fmaxf(acc[nt][r] + biasA[nt], 0.0f) : 0.0f;
        vs += __shfl_xor(vs, 16);
        vs += __shfl_xor(vs, 32);
        sr[nt] += vs;
      }
    }
    const float inv = (deg > 0) ? 1.0f / (float)deg : 0.0f;
    const int mr = wave*16 + m;
    MEAN[mr*136 + (2*q)*16 + p]     = f2b(sr[2*q] * inv);
    MEAN[mr*136 + (2*q + 1)*16 + p] = f2b(sr[2*q + 1] * inv);
  }
  __syncthreads();
  // restage W1b^T into WS
  for (int i = tid; i < 128*128; i += 256) { int k = i >> 7, n = i & 127; WS[n*136 + k] = f2b(w1b[i]); }
  __syncthreads();
  float biasB[8];
#pragma unroll
  for (int nt = 0; nt < 8; ++nt) biasB[nt] = b1b[nt*16 + p];
  bf16x8 a2[4];
#pragma unroll
  for (int s = 0; s < 4; ++s)
    a2[s] = *(const bf16x8*)&MEAN[(wave*16 + p)*136 + s*32 + q*8];
  f32x4 c2[8];
#pragma unroll
  for (int nt = 0; nt < 8; ++nt) c2[nt] = (f32x4){0.f,0.f,0.f,0.f};
#pragma unroll
  for (int nt = 0; nt < 8; ++nt)
#pragma unroll
    for (int s = 0; s < 4; ++s) {
      bf16x8 b = *(const bf16x8*)&WS[(nt*16 + p)*136 + s*32 + q*8];
      c2[nt] = __builtin_amdgcn_mfma_f32_16x16x32_bf16(a2[s], b, c2[nt], 0, 0, 0);
    }
  int degp = 0;
  {
    const int noden = n0 + wave*16 + p;
    if (noden < N_) degp = OFFA[noden + 1] - OFFA[noden];
  }
  int degq[4];
#pragma unroll
  for (int r = 0; r < 4; ++r) degq[r] = __shfl(degp, q*4 + r);
#pragma unroll
  for (int nt = 0; nt < 8; ++nt)
#pragma unroll
    for (int r = 0; r < 4; ++r) {
      const int orow = n0 + wave*16 + q*4 + r;
      if (orow < N_) {
        float v = (degq[r] > 0) ? fmaxf(c2[nt][r] + biasB[nt], 0.0f) : 0.0f;
        H[(size_t)orow*128 + nt*16 + p] = f2b(v);
      }
    }
}

// ==== fused GNN layer 2, atomic-free (input 128ch, output 64ch, no relu on node out) ====
__launch_bounds__(256)
__global__ void k_gnn2(const ushort_t* __restrict__ H,
                       const int* __restrict__ ESRC, const int* __restrict__ OFFA,
                       const float* __restrict__ w2a, const float* __restrict__ b2a,
                       const float* __restrict__ w2b, const float* __restrict__ b2b,
                       ushort_t* __restrict__ G)
{
  __shared__ __attribute__((aligned(16))) ushort_t WS[64*264];   // Wa^T then Wb^T(64x72)
  __shared__ __attribute__((aligned(16))) ushort_t MEAN[64*72];  // 64 nodes x 64ch bf16
  const int tid = threadIdx.x;
  for (int i = tid; i < 256*64; i += 256) { int k = i >> 6, n = i & 63; WS[n*264 + k] = f2b(w2a[i]); }
  __syncthreads();
  const int wave = tid >> 6, lane = tid & 63;
  const int p = lane & 15, q = lane >> 4;
  bf16x8 bfr[4][8];
#pragma unroll
  for (int nt = 0; nt < 4; ++nt)
#pragma unroll
    for (int s = 0; s < 8; ++s)
      bfr[nt][s] = *(const bf16x8*)&WS[(nt*16 + p)*264 + s*32 + q*8];
  float biasA[4];
#pragma unroll
  for (int nt = 0; nt < 4; ++nt) biasA[nt] = b2a[nt*16 + p];
  const int n0 = blockIdx.x * RN;

  for (int m = 0; m < 16; ++m) {
    const int node = n0 + wave*16 + m;
    int eb = 0, deg = 0;
    if (node < N_) { eb = OFFA[node]; deg = OFFA[node + 1] - eb; }
    const int nodeC = min(node, N_ - 1);
    const ushort_t* hd = H + (size_t)nodeC * 128;
    bf16x8 ad[4];
#pragma unroll
    for (int s = 0; s < 4; ++s) ad[s] = *(const bf16x8*)(hd + s*32 + q*8);
    float sr[4];
#pragma unroll
    for (int nt = 0; nt < 4; ++nt) sr[nt] = 0.0f;
    for (int t = 0; t*16 < deg; ++t) {
      const int e = eb + t*16 + p;
      const int src = (t*16 + p < deg) ? ESRC[e] : nodeC;
      const ushort_t* hs = H + (size_t)src * 128;
      bf16x8 as[4];
#pragma unroll
      for (int s = 0; s < 4; ++s) as[s] = *(const bf16x8*)(hs + s*32 + q*8);
      f32x4 acc[4];
#pragma unroll
      for (int nt = 0; nt < 4; ++nt) acc[nt] = (f32x4){0.f,0.f,0.f,0.f};
#pragma unroll
      for (int nt = 0; nt < 4; ++nt) {
#pragma unroll
        for (int s = 0; s < 4; ++s)
          acc[nt] = __builtin_amdgcn_mfma_f32_16x16x32_bf16(ad[s], bfr[nt][s], acc[nt], 0, 0, 0);
#pragma unroll
        for (int s = 0; s < 4; ++s)
          acc[nt] = __builtin_amdgcn_mfma_f32_16x16x32_bf16(as[s], bfr[nt][4 + s], acc[nt], 0, 0, 0);
      }
      const int base = t*16 + q*4;
#pragma unroll
      for (int nt = 0; nt < 4; ++nt) {
        float vs = 0.0f;
#pragma unroll
        for (int r = 0; r < 4; ++r)
          vs += (base + r < deg) ? fmaxf(acc[nt][r] + biasA[nt], 0.0f) : 0.0f;
        vs += __shfl_xor(vs, 16);
        vs += __shfl_xor(vs, 32);
        sr[nt] += vs;
      }
    }
    const float inv = (deg > 0) ? 1.0f / (float)deg : 0.0f;
    MEAN[(wave*16 + m)*72 + q*16 + p] = f2b(sr[q] * inv);
  }
  __syncthreads();
  // restage W2b^T (64x64) into WS
  for (int i = tid; i < 64*64; i += 256) { int k = i >> 6, n = i & 63; WS[n*72 + k] = f2b(w2b[i]); }
  __syncthreads();
  float biasB[4];
#pragma unroll
  for (int nt = 0; nt < 4; ++nt) biasB[nt] = b2b[nt*16 + p];
  bf16x8 a2[2];
#pragma unroll
  for (int s = 0; s < 2; ++s)
    a2[s] = *(const bf16x8*)&MEAN[(wave*16 + p)*72 + s*32 + q*8];
  f32x4 c2[4];
#pragma unroll
  for (int nt = 0; nt < 4; ++nt) c2[nt] = (f32x4){0.f,0.f,0.f,0.f};
#pragma unroll
  for (int nt = 0; nt < 4; ++nt)
#pragma unroll
    for (int s = 0; s < 2; ++s) {
      bf16x8 b = *(const bf16x8*)&WS[(nt*16 + p)*72 + s*32 + q*8];
      c2[nt] = __builtin_amdgcn_mfma_f32_16x16x32_bf16(a2[s], b, c2[nt], 0, 0, 0);
    }
  int degp = 0;
  {
    const int noden = n0 + wave*16 + p;
    if (noden < N_) degp = OFFA[noden + 1] - OFFA[noden];
  }
  int degq[4];
#pragma unroll
  for (int r = 0; r < 4; ++r) degq[r] = __shfl(degp, q*4 + r);
#pragma unroll
  for (int nt = 0; nt < 4; ++nt)
#pragma unroll
    for (int r = 0; r < 4; ++r) {
      const int orow = n0 + wave*16 + q*4 + r;
      if (orow < N_) {
        float v = (degq[r] > 0) ? (c2[nt][r] + biasB[nt]) : 0.0f;
        G[(size_t)orow*64 + nt*16 + p] = f2b(v);
      }
    }
}

// ---------------- mlp1 (MFMA): y1 = relu([state,g,me] @ W1 + b1); half-column blocks ----
__launch_bounds__(256)
__global__ void k_mlp1(const float* __restrict__ state, const ushort_t* __restrict__ gbuf,
                       const ushort_t* __restrict__ e16, const int* __restrict__ MODE,
                       const float* __restrict__ b1f, const float* __restrict__ w1,
                       ushort_t* __restrict__ y1)
{
  __shared__ __attribute__((aligned(16))) ushort_t Wt[128*168];
  const int tid = threadIdx.x;
  const int cb = (blockIdx.x & 1) * 128;
  for (int i = tid; i < 128*160; i += 256) {
    int n = i / 160, k = i - n*160;
    Wt[n*168 + k] = (k < 144) ? f2b(w1[k*256 + cb + n]) : (ushort_t)0;
  }
  __syncthreads();
  const int wave = tid >> 6, lane = tid & 63;
  const int p = lane & 15, q = lane >> 4;
  float bias[8];
#pragma unroll
  for (int nt = 0; nt < 8; ++nt) bias[nt] = b1f[cb + nt*16 + p];
  bf16x8 zed;
#pragma unroll
  for (int j = 0; j < 8; ++j) zed[j] = (__bf16)0.0f;
  const int nwaves = (gridDim.x >> 1) * 4;
  for (int t = (blockIdx.x >> 1)*4 + wave; t < N_/16; t += nwaves) {
    const int base = t * 16;
    const int node = base + p;
    bf16x8 afr[5];
    afr[0] = cvt8(state + (size_t)node*64 + q*8);
    afr[1] = cvt8(state + (size_t)node*64 + 32 + q*8);
    afr[2] = *(const bf16x8*)(gbuf + (size_t)node*64 + q*8);
    afr[3] = *(const bf16x8*)(gbuf + (size_t)node*64 + 32 + q*8);
    afr[4] = (q < 2) ? *(const bf16x8*)(e16 + (size_t)MODE[node]*16 + q*8) : zed;
    f32x4 acc[8];
#pragma unroll
    for (int nt = 0; nt < 8; ++nt) acc[nt] = (f32x4){0.f,0.f,0.f,0.f};
#pragma unroll
    for (int nt = 0; nt < 8; ++nt)
#pragma unroll
      for (int s = 0; s < 5; ++s) {
        bf16x8 b = *(const bf16x8*)&Wt[(nt*16 + p)*168 + s*32 + q*8];
        acc[nt] = __builtin_amdgcn_mfma_f32_16x16x32_bf16(afr[s], b, acc[nt], 0, 0, 0);
      }
#pragma unroll
    for (int nt = 0; nt < 8; ++nt)
#pragma unroll
      for (int r = 0; r < 4; ++r) {
        float v = fmaxf(acc[nt][r] + bias[nt], 0.0f);
        y1[(size_t)(base + q*4 + r)*256 + cb + nt*16 + p] = f2b(v);
      }
  }
}

// ---------------- mlp2 (MFMA): y2 = relu(y1 @ W2 + b2); half-column blocks ----
__launch_bounds__(256)
__global__ void k_mlp2(const ushort_t* __restrict__ y1, const float* __restrict__ w2,
                       const float* __restrict__ b2f, ushort_t* __restrict__ y2)
{
  __shared__ __attribute__((aligned(16))) ushort_t Wt[128*264];
  const int tid = threadIdx.x;
  const int cb = (blockIdx.x & 1) * 128;
  for (int i = tid; i < 128*256; i += 256) {
    int n = i >> 8, k = i & 255;
    Wt[n*264 + k] = f2b(w2[k*256 + cb + n]);
  }
  __syncthreads();
  const int wave = tid >> 6, lane = tid & 63;
  const int p = lane & 15, q = lane >> 4;
  float bias[8];
#pragma unroll
  for (int nt = 0; nt < 8; ++nt) bias[nt] = b2f[cb + nt*16 + p];
  const int nwaves = (gridDim.x >> 1) * 4;
  for (int t = (blockIdx.x >> 1)*4 + wave; t < N_/16; t += nwaves) {
    const int base = t * 16;
    bf16x8 afr[8];
#pragma unroll
    for (int s = 0; s < 8; ++s)
      afr[s] = *(const bf16x8*)(y1 + (size_t)(base + p)*256 + s*32 + q*8);
    f32x4 acc[8];
#pragma unroll
    for (int nt = 0; nt < 8; ++nt) acc[nt] = (f32x4){0.f,0.f,0.f,0.f};
#pragma unroll
    for (int nt = 0; nt < 8; ++nt)
#pragma unroll
      for (int s = 0; s < 8; ++s) {
        bf16x8 b = *(const bf16x8*)&Wt[(nt*16 + p)*264 + s*32 + q*8];
        acc[nt] = __builtin_amdgcn_mfma_f32_16x16x32_bf16(afr[s], b, acc[nt], 0, 0, 0);
      }
#pragma unroll
    for (int nt = 0; nt < 8; ++nt)
#pragma unroll
      for (int r = 0; r < 4; ++r) {
        float v = fmaxf(acc[nt][r] + bias[nt], 0.0f);
        y2[(size_t)(base + q*4 + r)*256 + cb + nt*16 + p] = f2b(v);
      }
  }
}

// ---------------- heads (MFMA): f32 out ----
__launch_bounds__(256)
__global__ void k_heads(const ushort_t* __restrict__ y2, const ushort_t* __restrict__ wth,
                        const float* __restrict__ bm, const float* __restrict__ bs,
                        float* __restrict__ out)
{
  const int tid = threadIdx.x;
  const int wave = tid >> 6, lane = tid & 63;
  const int p = lane & 15, q = lane >> 4;
  bf16x8 bfr[8];
#pragma unroll
  for (int s = 0; s < 8; ++s)
    bfr[s] = *(const bf16x8*)(wth + (size_t)p*256 + s*32 + q*8);
  float bias = (p < 8) ? bm[p] : bs[p - 8];
  const int nwaves = gridDim.x * 4;
  for (int t = blockIdx.x*4 + wave; t < N_/16; t += nwaves) {
    const int base = t * 16;
    f32x4 acc = (f32x4){0.f,0.f,0.f,0.f};
#pragma unroll
    for (int s = 0; s < 8; ++s) {
      bf16x8 a = *(const bf16x8*)(y2 + (size_t)(base + p)*256 + s*32 + q*8);
      acc = __builtin_amdgcn_mfma_f32_16x16x32_bf16(a, bfr[s], acc, 0, 0, 0);
    }
#pragma unroll
    for (int r = 0; r < 4; ++r) {
      int node = base + q*4 + r;
      float v = acc[r] + bias;
      if (p < 8) {
        out[(size_t)node*8 + p] = v;
      } else {
        v = fminf(fmaxf(v, -20.f), 2.f);
        out[(size_t)N_*8 + (size_t)node*8 + (p - 8)] = v;
      }
    }
  }
}

extern "C" void kernel_launch(void* const* d_in, const int* in_sizes, int n_in,
                              void* d_out, int out_size, void* d_ws, size_t ws_size,
                              hipStream_t stream)
{
  float* out = (float*)d_out;

  float code = 0.0f;
  if      (n_in != 21)                 code = 1.0e6f;
  else if (in_sizes[0]  != 3200000)    code = 2.0e6f;
  else if (in_sizes[1]  != 3200000)    code = 3.0e6f;
  else if (in_sizes[2]  != 1600000)    code = 4.0e6f;
  else if (in_sizes[3]  != 50000)      code = 5.0e6f;
  else if (in_sizes[4]  != 16384)      code = 6.0e6f;
  else if (in_sizes[13] != 36864)      code = 7.0e6f;
  else if (in_sizes[15] != 65536)      code = 8.0e6f;
  else if (in_sizes[17] != 2048)       code = 9.0e6f;
  else if (out_size     != 800000)     code = 1.0e7f;
  else if (ws_size      < WS_NEED)     code = 1.1e7f;
  if (code != 0.0f) {
    k_code<<<1, 64, 0, stream>>>(out, code);
    return;
  }

  const float* state = (const float*)d_in[0];
  const float* xn    = (const float*)d_in[1];
  const int*   ei    = (const int*)d_in[2];
  const int*   mo    = (const int*)d_in[3];
  const float* w1a   = (const float*)d_in[4];
  const float* b1a   = (const float*)d_in[5];
  const float* w1b   = (const float*)d_in[6];
  const float* b1b   = (const float*)d_in[7];
  const float* w2a   = (const float*)d_in[8];
  const float* b2a   = (const float*)d_in[9];
  const float* w2b   = (const float*)d_in[10];
  const float* b2b   = (const float*)d_in[11];
  const float* emb   = (const float*)d_in[12];
  const float* w1    = (const float*)d_in[13];
  const float* b1    = (const float*)d_in[14];
  const float* w2    = (const float*)d_in[15];
  const float* b2    = (const float*)d_in[16];
  const float* wm    = (const float*)d_in[17];
  const float* bm    = (const float*)d_in[18];
  const float* wsw   = (const float*)d_in[19];
  const float* bs    = (const float*)d_in[20];

  char* ws = (char*)d_ws;
  ushort_t* XB   = (ushort_t*)(ws + OFF_XB);
  int*      SRC  = (int*)(ws + OFF_SRC);
  int*      DST  = (int*)(ws + OFF_DST);
  ushort_t* H    = (ushort_t*)(ws + OFF_H);
  int*      ESRC = (int*)(ws + OFF_ESRC);
  int*      CUR  = (int*)(ws + OFF_CUR);
  ushort_t* G    = (ushort_t*)(ws + OFF_G);
  int*      OFFA = (int*)(ws + OFF_OFFA);
  int*      MODE = (int*)(ws + OFF_MODE);
  ushort_t* WTH  = (ushort_t*)(ws + OFF_WTH);
  ushort_t* E16  = (ushort_t*)(ws + OFF_E16);
  int*      FLG  = (int*)(ws + OFF_FLAG);
  ushort_t* Y1   = (ushort_t*)(ws + OFF_Y1);
  ushort_t* Y2   = (ushort_t*)(ws + OFF_Y2);

  hipMemsetAsync(CUR, 0, (size_t)N_ * 4, stream);
  k_detect <<<1,    256,  0, stream>>>(ei, mo, FLG);
  k_cvt    <<<1600, 256,  0, stream>>>(ei, mo, FLG, SRC, DST, MODE, CUR);
  k_scan   <<<1,    1024, 0, stream>>>(CUR, OFFA);
  k_scatter<<<1600, 256,  0, stream>>>(SRC, DST, CUR, ESRC);
  k_prep   <<<12517,256,  0, stream>>>(xn, wm, wsw, emb, XB, WTH, E16);
  k_gnn1   <<<NB,   256,  0, stream>>>(XB, ESRC, OFFA, w1a, b1a, w1b, b1b, H);
  k_gnn2   <<<NB,   256,  0, stream>>>(H, ESRC, OFFA, w2a, b2a, w2b, b2b, G);
  k_mlp1   <<<256,  256,  0, stream>>>(state, G, E16, MODE, b1, w1, Y1);
  k_mlp2   <<<256,  256,  0, stream>>>(Y1, w2, b2, Y2);
  k_heads  <<<128,  256,  0, stream>>>(Y2, WTH, bm, bs, out);
}

// Round 11
// 479.693 us; speedup vs baseline: 2.9624x; 1.2378x over previous
//
#include <hip/hip_runtime.h>

typedef unsigned short ushort_t;
typedef unsigned int uint32;

typedef __bf16 bf16x8 __attribute__((ext_vector_type(8)));
typedef float f32x4 __attribute__((ext_vector_type(4)));

#define DEVI static __device__ __forceinline__

constexpr int N_ = 50000;
constexpr int E_ = 800000;
constexpr int RN = 64;                    // dst nodes per block in fused GNN kernels
constexpr int NB = (N_ + RN - 1) / RN;    // 782
constexpr int SB = 196;                   // scan blocks (196*256 = 50176 >= N_)

// ---- workspace layout (bytes) ----
constexpr size_t OFF_XB   = 0;          // bf16 N*64   (dead after gnn1)
constexpr size_t OFF_SRC  = 6400000;    // int E unsorted (dead after scatter)
constexpr size_t OFF_DST  = 9600000;    // int E unsorted (dead after scatter)
constexpr size_t OFF_Y1   = 0;          // bf16 N*256 (mlp phase; aliases XB/SRC/DST)
constexpr size_t OFF_H    = 25600000;   // bf16 N*128 (dead after gnn2)
constexpr size_t OFF_ESRC = 38400000;   // int E sorted-by-dst src
constexpr size_t OFF_CUR  = 44800000;   // int N histogram/cursors (zeroed each launch)
constexpr size_t OFF_Y2   = 25600000;   // bf16 N*256 (mlp phase; aliases H/ESRC/CUR)
constexpr size_t OFF_G    = 51200000;   // bf16 N*64
constexpr size_t OFF_OFFA = 57600000;   // int N+1 prefix sums
constexpr size_t OFF_MODE = 57800064;   // int N
constexpr size_t OFF_WTH  = 58000064;   // bf16 16*256 head weights^T
constexpr size_t OFF_E16  = 58008256;   // bf16 emb 3*16 (pad)
constexpr size_t OFF_FLAG = 58008384;   // int32 x 4
constexpr size_t OFF_BS   = 58008448;   // int 256 block sums
constexpr size_t WS_NEED  = 58009472;

DEVI ushort_t f2b(float f){ union { float f; uint32 u; } x; x.f = f;
  uint32 r = (x.u + 0x7fffu + ((x.u >> 16) & 1u)) >> 16; return (ushort_t)r; }

DEVI bf16x8 cvt8(const float* p){
  f32x4 u = *(const f32x4*)p, v = *(const f32x4*)(p + 4);
  bf16x8 r;
#pragma unroll
  for (int j = 0; j < 4; ++j) r[j] = (__bf16)u[j];
#pragma unroll
  for (int j = 0; j < 4; ++j) r[4+j] = (__bf16)v[j];
  return r;
}

// ---- diagnostic ----
__global__ void k_code(float* out, float code){
  if (threadIdx.x == 0 && blockIdx.x == 0) out[0] = code;
}

// ---- detect int64 vs int32 layout (proven int32; kept as insurance) ----
__launch_bounds__(256)
__global__ void k_detect(const int* __restrict__ ei, const int* __restrict__ mo,
                         int* __restrict__ flags)
{
  __shared__ int red[2];
  if (threadIdx.x == 0) { red[0] = 0; red[1] = 0; }
  __syncthreads();
  int a = 0, b = 0;
  for (int i = threadIdx.x; i < 4096; i += 256) a |= ei[2*i + 1];
  for (int i = threadIdx.x; i < 2048; i += 256) b |= mo[2*i + 1];
  atomicOr(&red[0], a);
  atomicOr(&red[1], b);
  __syncthreads();
  if (threadIdx.x == 0) { flags[0] = (red[0] == 0) ? 1 : 0; flags[1] = (red[1] == 0) ? 1 : 0; }
}

// ---- normalize indices + histogram dst into CUR (CUR pre-zeroed); int atomics = native ----
__launch_bounds__(256)
__global__ void k_cvt(const int* __restrict__ ei, const int* __restrict__ mo,
                      const int* __restrict__ flags,
                      int* __restrict__ SRC, int* __restrict__ DST, int* __restrict__ MODE,
                      int* __restrict__ CUR)
{
  const int fE = flags[0], fM = flags[1];
  const int g = gridDim.x * 256;
  for (int e = blockIdx.x*256 + threadIdx.x; e < E_; e += g) {
    int s = fE ? ei[2*e]        : ei[e];
    int d = fE ? ei[2*E_ + 2*e] : ei[E_ + e];
    SRC[e] = s; DST[e] = d;
    atomicAdd(&CUR[d], 1);
  }
  for (int n = blockIdx.x*256 + threadIdx.x; n < N_; n += g) {
    MODE[n] = fM ? mo[2*n] : mo[n];
  }
}

// ---- hierarchical scan, phase A: per-block degree sums ----
__launch_bounds__(256)
__global__ void k_scanA(const int* __restrict__ CUR, int* __restrict__ BS)
{
  __shared__ int ls[4];
  const int t = threadIdx.x;
  const int i = blockIdx.x*256 + t;
  int v = (i < N_) ? CUR[i] : 0;
#pragma unroll
  for (int off = 32; off; off >>= 1) v += __shfl_down(v, off);
  if ((t & 63) == 0) ls[t >> 6] = v;
  __syncthreads();
  if (t == 0) BS[blockIdx.x] = ls[0] + ls[1] + ls[2] + ls[3];
}

// ---- phase B: one block scans SB block-sums (exclusive) in-place; total -> OFFA[N] ----
__launch_bounds__(256)
__global__ void k_scanB(int* __restrict__ BS, int* __restrict__ OFFA)
{
  __shared__ int ls[256];
  const int t = threadIdx.x;
  int v = (t < SB) ? BS[t] : 0;
  ls[t] = v;
  __syncthreads();
#pragma unroll
  for (int off = 1; off < 256; off <<= 1) {
    int u = (t >= off) ? ls[t - off] : 0;
    __syncthreads();
    ls[t] += u;
    __syncthreads();
  }
  if (t < SB) BS[t] = ls[t] - v;          // exclusive
  if (t == 255) OFFA[N_] = ls[255];
}

// ---- phase C: per-block LDS scan + base -> OFFA and CUR(=prefix cursor) ----
__launch_bounds__(256)
__global__ void k_scanC(const int* __restrict__ BS, int* __restrict__ CUR,
                        int* __restrict__ OFFA)
{
  __shared__ int ls[256];
  const int t = threadIdx.x;
  const int i = blockIdx.x*256 + t;
  int v = (i < N_) ? CUR[i] : 0;
  ls[t] = v;
  __syncthreads();
#pragma unroll
  for (int off = 1; off < 256; off <<= 1) {
    int u = (t >= off) ? ls[t - off] : 0;
    __syncthreads();
    ls[t] += u;
    __syncthreads();
  }
  if (i < N_) {
    int pref = BS[blockIdx.x] + ls[t] - v;  // exclusive prefix
    OFFA[i] = pref;
    CUR[i]  = pref;
  }
}

// ---- scatter edge srcs into dst-sorted order ----
__launch_bounds__(256)
__global__ void k_scatter(const int* __restrict__ SRC, const int* __restrict__ DST,
                          int* __restrict__ CUR, int* __restrict__ ESRC)
{
  const int g = gridDim.x * 256;
  for (int e = blockIdx.x*256 + threadIdx.x; e < E_; e += g) {
    int d = DST[e];
    int pos = atomicAdd(&CUR[d], 1);
    ESRC[pos] = SRC[e];
  }
}

// ---- prep: x_nodes f32->bf16, head W^T bf16, emb bf16 ----
__launch_bounds__(256)
__global__ void k_prep(const float* __restrict__ xn, const float* __restrict__ wm,
                       const float* __restrict__ wsw, const float* __restrict__ emb,
                       ushort_t* __restrict__ xb, ushort_t* __restrict__ wth,
                       ushort_t* __restrict__ e16)
{
  int i = blockIdx.x * 256 + threadIdx.x;
  if (i < N_*64) {
    xb[i] = f2b(xn[i]);
  } else if (i < N_*64 + 4096) {
    int j = i - N_*64; int n = j >> 8, k = j & 255;
    wth[j] = f2b(n < 8 ? wm[k*8 + n] : wsw[k*8 + (n - 8)]);
  } else if (i < N_*64 + 4096 + 48) {
    int j = i - (N_*64 + 4096);
    e16[j] = f2b(emb[j]);
  }
}

// ==== fused GNN layer 1, atomic-free ====
__launch_bounds__(256)
__global__ void k_gnn1(const ushort_t* __restrict__ XB,
                       const int* __restrict__ ESRC, const int* __restrict__ OFFA,
                       const float* __restrict__ w1a, const float* __restrict__ b1a,
                       const float* __restrict__ w1b, const float* __restrict__ b1b,
                       ushort_t* __restrict__ H)
{
  __shared__ __attribute__((aligned(16))) ushort_t WS[128*136];   // Wa^T then Wb^T
  __shared__ __attribute__((aligned(16))) ushort_t MEAN[64*136];  // 64 nodes x 128ch bf16
  const int tid = threadIdx.x;
  for (int i = tid; i < 128*128; i += 256) { int k = i >> 7, n = i & 127; WS[n*136 + k] = f2b(w1a[i]); }
  __syncthreads();
  const int wave = tid >> 6, lane = tid & 63;
  const int p = lane & 15, q = lane >> 4;
  bf16x8 bfr[8][4];
#pragma unroll
  for (int nt = 0; nt < 8; ++nt)
#pragma unroll
    for (int s = 0; s < 4; ++s)
      bfr[nt][s] = *(const bf16x8*)&WS[(nt*16 + p)*136 + s*32 + q*8];
  float biasA[8];
#pragma unroll
  for (int nt = 0; nt < 8; ++nt) biasA[nt] = b1a[nt*16 + p];
  const int n0 = blockIdx.x * RN;

  for (int m = 0; m < 16; ++m) {
    const int node = n0 + wave*16 + m;
    int eb = 0, deg = 0;
    if (node < N_) { eb = OFFA[node]; deg = OFFA[node + 1] - eb; }
    const int nodeC = min(node, N_ - 1);
    const ushort_t* xd = XB + (size_t)nodeC * 64;
    bf16x8 ad0 = *(const bf16x8*)(xd + q*8);
    bf16x8 ad1 = *(const bf16x8*)(xd + 32 + q*8);
    float sr[8];
#pragma unroll
    for (int nt = 0; nt < 8; ++nt) sr[nt] = 0.0f;
    for (int t = 0; t*16 < deg; ++t) {
      const int e = eb + t*16 + p;
      const int src = (t*16 + p < deg) ? ESRC[e] : nodeC;
      const ushort_t* xs = XB + (size_t)src * 64;
      bf16x8 as0 = *(const bf16x8*)(xs + q*8);
      bf16x8 as1 = *(const bf16x8*)(xs + 32 + q*8);
      f32x4 acc[8];
#pragma unroll
      for (int nt = 0; nt < 8; ++nt) acc[nt] = (f32x4){0.f,0.f,0.f,0.f};
#pragma unroll
      for (int nt = 0; nt < 8; ++nt) {
        acc[nt] = __builtin_amdgcn_mfma_f32_16x16x32_bf16(ad0, bfr[nt][0], acc[nt], 0, 0, 0);
        acc[nt] = __builtin_amdgcn_mfma_f32_16x16x32_bf16(ad1, bfr[nt][1], acc[nt], 0, 0, 0);
        acc[nt] = __builtin_amdgcn_mfma_f32_16x16x32_bf16(as0, bfr[nt][2], acc[nt], 0, 0, 0);
        acc[nt] = __builtin_amdgcn_mfma_f32_16x16x32_bf16(as1, bfr[nt][3], acc[nt], 0, 0, 0);
      }
      const int base = t*16 + q*4;
#pragma unroll
      for (int nt = 0; nt < 8; ++nt) {
        float vs = 0.0f;
#pragma unroll
        for (int r = 0; r < 4; ++r)
          vs += (base + r < deg) ? fmaxf(acc[nt][r] + biasA[nt], 0.0f) : 0.0f;
        vs += __shfl_xor(vs, 16);
        vs += __shfl_xor(vs, 32);
        sr[nt] += vs;
      }
    }
    const float inv = (deg > 0) ? 1.0f / (float)deg : 0.0f;
    const int mr = wave*16 + m;
    MEAN[mr*136 + (2*q)*16 + p]     = f2b(sr[2*q] * inv);
    MEAN[mr*136 + (2*q + 1)*16 + p] = f2b(sr[2*q + 1] * inv);
  }
  __syncthreads();
  // restage W1b^T into WS
  for (int i = tid; i < 128*128; i += 256) { int k = i >> 7, n = i & 127; WS[n*136 + k] = f2b(w1b[i]); }
  __syncthreads();
  float biasB[8];
#pragma unroll
  for (int nt = 0; nt < 8; ++nt) biasB[nt] = b1b[nt*16 + p];
  bf16x8 a2[4];
#pragma unroll
  for (int s = 0; s < 4; ++s)
    a2[s] = *(const bf16x8*)&MEAN[(wave*16 + p)*136 + s*32 + q*8];
  f32x4 c2[8];
#pragma unroll
  for (int nt = 0; nt < 8; ++nt) c2[nt] = (f32x4){0.f,0.f,0.f,0.f};
#pragma unroll
  for (int nt = 0; nt < 8; ++nt)
#pragma unroll
    for (int s = 0; s < 4; ++s) {
      bf16x8 b = *(const bf16x8*)&WS[(nt*16 + p)*136 + s*32 + q*8];
      c2[nt] = __builtin_amdgcn_mfma_f32_16x16x32_bf16(a2[s], b, c2[nt], 0, 0, 0);
    }
  int degp = 0;
  {
    const int noden = n0 + wave*16 + p;
    if (noden < N_) degp = OFFA[noden + 1] - OFFA[noden];
  }
  int degq[4];
#pragma unroll
  for (int r = 0; r < 4; ++r) degq[r] = __shfl(degp, q*4 + r);
#pragma unroll
  for (int nt = 0; nt < 8; ++nt)
#pragma unroll
    for (int r = 0; r < 4; ++r) {
      const int orow = n0 + wave*16 + q*4 + r;
      if (orow < N_) {
        float v = (degq[r] > 0) ? fmaxf(c2[nt][r] + biasB[nt], 0.0f) : 0.0f;
        H[(size_t)orow*128 + nt*16 + p] = f2b(v);
      }
    }
}

// ==== fused GNN layer 2, atomic-free (input 128ch, output 64ch, no relu on node out) ====
__launch_bounds__(256)
__global__ void k_gnn2(const ushort_t* __restrict__ H,
                       const int* __restrict__ ESRC, const int* __restrict__ OFFA,
                       const float* __restrict__ w2a, const float* __restrict__ b2a,
                       const float* __restrict__ w2b, const float* __restrict__ b2b,
                       ushort_t* __restrict__ G)
{
  __shared__ __attribute__((aligned(16))) ushort_t WS[64*264];   // Wa^T then Wb^T(64x72)
  __shared__ __attribute__((aligned(16))) ushort_t MEAN[64*72];  // 64 nodes x 64ch bf16
  const int tid = threadIdx.x;
  for (int i = tid; i < 256*64; i += 256) { int k = i >> 6, n = i & 63; WS[n*264 + k] = f2b(w2a[i]); }
  __syncthreads();
  const int wave = tid >> 6, lane = tid & 63;
  const int p = lane & 15, q = lane >> 4;
  bf16x8 bfr[4][8];
#pragma unroll
  for (int nt = 0; nt < 4; ++nt)
#pragma unroll
    for (int s = 0; s < 8; ++s)
      bfr[nt][s] = *(const bf16x8*)&WS[(nt*16 + p)*264 + s*32 + q*8];
  float biasA[4];
#pragma unroll
  for (int nt = 0; nt < 4; ++nt) biasA[nt] = b2a[nt*16 + p];
  const int n0 = blockIdx.x * RN;

  for (int m = 0; m < 16; ++m) {
    const int node = n0 + wave*16 + m;
    int eb = 0, deg = 0;
    if (node < N_) { eb = OFFA[node]; deg = OFFA[node + 1] - eb; }
    const int nodeC = min(node, N_ - 1);
    const ushort_t* hd = H + (size_t)nodeC * 128;
    bf16x8 ad[4];
#pragma unroll
    for (int s = 0; s < 4; ++s) ad[s] = *(const bf16x8*)(hd + s*32 + q*8);
    float sr[4];
#pragma unroll
    for (int nt = 0; nt < 4; ++nt) sr[nt] = 0.0f;
    for (int t = 0; t*16 < deg; ++t) {
      const int e = eb + t*16 + p;
      const int src = (t*16 + p < deg) ? ESRC[e] : nodeC;
      const ushort_t* hs = H + (size_t)src * 128;
      bf16x8 as[4];
#pragma unroll
      for (int s = 0; s < 4; ++s) as[s] = *(const bf16x8*)(hs + s*32 + q*8);
      f32x4 acc[4];
#pragma unroll
      for (int nt = 0; nt < 4; ++nt) acc[nt] = (f32x4){0.f,0.f,0.f,0.f};
#pragma unroll
      for (int nt = 0; nt < 4; ++nt) {
#pragma unroll
        for (int s = 0; s < 4; ++s)
          acc[nt] = __builtin_amdgcn_mfma_f32_16x16x32_bf16(ad[s], bfr[nt][s], acc[nt], 0, 0, 0);
#pragma unroll
        for (int s = 0; s < 4; ++s)
          acc[nt] = __builtin_amdgcn_mfma_f32_16x16x32_bf16(as[s], bfr[nt][4 + s], acc[nt], 0, 0, 0);
      }
      const int base = t*16 + q*4;
#pragma unroll
      for (int nt = 0; nt < 4; ++nt) {
        float vs = 0.0f;
#pragma unroll
        for (int r = 0; r < 4; ++r)
          vs += (base + r < deg) ? fmaxf(acc[nt][r] + biasA[nt], 0.0f) : 0.0f;
        vs += __shfl_xor(vs, 16);
        vs += __shfl_xor(vs, 32);
        sr[nt] += vs;
      }
    }
    const float inv = (deg > 0) ? 1.0f / (float)deg : 0.0f;
    MEAN[(wave*16 + m)*72 + q*16 + p] = f2b(sr[q] * inv);
  }
  __syncthreads();
  // restage W2b^T (64x64) into WS
  for (int i = tid; i < 64*64; i += 256) { int k = i >> 6, n = i & 63; WS[n*72 + k] = f2b(w2b[i]); }
  __syncthreads();
  float biasB[4];
#pragma unroll
  for (int nt = 0; nt < 4; ++nt) biasB[nt] = b2b[nt*16 + p];
  bf16x8 a2[2];
#pragma unroll
  for (int s = 0; s < 2; ++s)
    a2[s] = *(const bf16x8*)&MEAN[(wave*16 + p)*72 + s*32 + q*8];
  f32x4 c2[4];
#pragma unroll
  for (int nt = 0; nt < 4; ++nt) c2[nt] = (f32x4){0.f,0.f,0.f,0.f};
#pragma unroll
  for (int nt = 0; nt < 4; ++nt)
#pragma unroll
    for (int s = 0; s < 2; ++s) {
      bf16x8 b = *(const bf16x8*)&WS[(nt*16 + p)*72 + s*32 + q*8];
      c2[nt] = __builtin_amdgcn_mfma_f32_16x16x32_bf16(a2[s], b, c2[nt], 0, 0, 0);
    }
  int degp = 0;
  {
    const int noden = n0 + wave*16 + p;
    if (noden < N_) degp = OFFA[noden + 1] - OFFA[noden];
  }
  int degq[4];
#pragma unroll
  for (int r = 0; r < 4; ++r) degq[r] = __shfl(degp, q*4 + r);
#pragma unroll
  for (int nt = 0; nt < 4; ++nt)
#pragma unroll
    for (int r = 0; r < 4; ++r) {
      const int orow = n0 + wave*16 + q*4 + r;
      if (orow < N_) {
        float v = (degq[r] > 0) ? (c2[nt][r] + biasB[nt]) : 0.0f;
        G[(size_t)orow*64 + nt*16 + p] = f2b(v);
      }
    }
}

// ---------------- mlp1 (MFMA): y1 = relu([state,g,me] @ W1 + b1); half-column blocks ----
__launch_bounds__(256)
__global__ void k_mlp1(const float* __restrict__ state, const ushort_t* __restrict__ gbuf,
                       const ushort_t* __restrict__ e16, const int* __restrict__ MODE,
                       const float* __restrict__ b1f, const float* __restrict__ w1,
                       ushort_t* __restrict__ y1)
{
  __shared__ __attribute__((aligned(16))) ushort_t Wt[128*168];
  const int tid = threadIdx.x;
  const int cb = (blockIdx.x & 1) * 128;
  for (int i = tid; i < 128*160; i += 256) {
    int n = i / 160, k = i - n*160;
    Wt[n*168 + k] = (k < 144) ? f2b(w1[k*256 + cb + n]) : (ushort_t)0;
  }
  __syncthreads();
  const int wave = tid >> 6, lane = tid & 63;
  const int p = lane & 15, q = lane >> 4;
  float bias[8];
#pragma unroll
  for (int nt = 0; nt < 8; ++nt) bias[nt] = b1f[cb + nt*16 + p];
  bf16x8 zed;
#pragma unroll
  for (int j = 0; j < 8; ++j) zed[j] = (__bf16)0.0f;
  const int nwaves = (gridDim.x >> 1) * 4;
  for (int t = (blockIdx.x >> 1)*4 + wave; t < N_/16; t += nwaves) {
    const int base = t * 16;
    const int node = base + p;
    bf16x8 afr[5];
    afr[0] = cvt8(state + (size_t)node*64 + q*8);
    afr[1] = cvt8(state + (size_t)node*64 + 32 + q*8);
    afr[2] = *(const bf16x8*)(gbuf + (size_t)node*64 + q*8);
    afr[3] = *(const bf16x8*)(gbuf + (size_t)node*64 + 32 + q*8);
    afr[4] = (q < 2) ? *(const bf16x8*)(e16 + (size_t)MODE[node]*16 + q*8) : zed;
    f32x4 acc[8];
#pragma unroll
    for (int nt = 0; nt < 8; ++nt) acc[nt] = (f32x4){0.f,0.f,0.f,0.f};
#pragma unroll
    for (int nt = 0; nt < 8; ++nt)
#pragma unroll
      for (int s = 0; s < 5; ++s) {
        bf16x8 b = *(const bf16x8*)&Wt[(nt*16 + p)*168 + s*32 + q*8];
        acc[nt] = __builtin_amdgcn_mfma_f32_16x16x32_bf16(afr[s], b, acc[nt], 0, 0, 0);
      }
#pragma unroll
    for (int nt = 0; nt < 8; ++nt)
#pragma unroll
      for (int r = 0; r < 4; ++r) {
        float v = fmaxf(acc[nt][r] + bias[nt], 0.0f);
        y1[(size_t)(base + q*4 + r)*256 + cb + nt*16 + p] = f2b(v);
      }
  }
}

// ---------------- mlp2 (MFMA): y2 = relu(y1 @ W2 + b2); half-column blocks ----
__launch_bounds__(256)
__global__ void k_mlp2(const ushort_t* __restrict__ y1, const float* __restrict__ w2,
                       const float* __restrict__ b2f, ushort_t* __restrict__ y2)
{
  __shared__ __attribute__((aligned(16))) ushort_t Wt[128*264];
  const int tid = threadIdx.x;
  const int cb = (blockIdx.x & 1) * 128;
  for (int i = tid; i < 128*256; i += 256) {
    int n = i >> 8, k = i & 255;
    Wt[n*264 + k] = f2b(w2[k*256 + cb + n]);
  }
  __syncthreads();
  const int wave = tid >> 6, lane = tid & 63;
  const int p = lane & 15, q = lane >> 4;
  float bias[8];
#pragma unroll
  for (int nt = 0; nt < 8; ++nt) bias[nt] = b2f[cb + nt*16 + p];
  const int nwaves = (gridDim.x >> 1) * 4;
  for (int t = (blockIdx.x >> 1)*4 + wave; t < N_/16; t += nwaves) {
    const int base = t * 16;
    bf16x8 afr[8];
#pragma unroll
    for (int s = 0; s < 8; ++s)
      afr[s] = *(const bf16x8*)(y1 + (size_t)(base + p)*256 + s*32 + q*8);
    f32x4 acc[8];
#pragma unroll
    for (int nt = 0; nt < 8; ++nt) acc[nt] = (f32x4){0.f,0.f,0.f,0.f};
#pragma unroll
    for (int nt = 0; nt < 8; ++nt)
#pragma unroll
      for (int s = 0; s < 8; ++s) {
        bf16x8 b = *(const bf16x8*)&Wt[(nt*16 + p)*264 + s*32 + q*8];
        acc[nt] = __builtin_amdgcn_mfma_f32_16x16x32_bf16(afr[s], b, acc[nt], 0, 0, 0);
      }
#pragma unroll
    for (int nt = 0; nt < 8; ++nt)
#pragma unroll
      for (int r = 0; r < 4; ++r) {
        float v = fmaxf(acc[nt][r] + bias[nt], 0.0f);
        y2[(size_t)(base + q*4 + r)*256 + cb + nt*16 + p] = f2b(v);
      }
  }
}

// ---------------- heads (MFMA): f32 out ----
__launch_bounds__(256)
__global__ void k_heads(const ushort_t* __restrict__ y2, const ushort_t* __restrict__ wth,
                        const float* __restrict__ bm, const float* __restrict__ bs,
                        float* __restrict__ out)
{
  const int tid = threadIdx.x;
  const int wave = tid >> 6, lane = tid & 63;
  const int p = lane & 15, q = lane >> 4;
  bf16x8 bfr[8];
#pragma unroll
  for (int s = 0; s < 8; ++s)
    bfr[s] = *(const bf16x8*)(wth + (size_t)p*256 + s*32 + q*8);
  float bias = (p < 8) ? bm[p] : bs[p - 8];
  const int nwaves = gridDim.x * 4;
  for (int t = blockIdx.x*4 + wave; t < N_/16; t += nwaves) {
    const int base = t * 16;
    f32x4 acc = (f32x4){0.f,0.f,0.f,0.f};
#pragma unroll
    for (int s = 0; s < 8; ++s) {
      bf16x8 a = *(const bf16x8*)(y2 + (size_t)(base + p)*256 + s*32 + q*8);
      acc = __builtin_amdgcn_mfma_f32_16x16x32_bf16(a, bfr[s], acc, 0, 0, 0);
    }
#pragma unroll
    for (int r = 0; r < 4; ++r) {
      int node = base + q*4 + r;
      float v = acc[r] + bias;
      if (p < 8) {
        out[(size_t)node*8 + p] = v;
      } else {
        v = fminf(fmaxf(v, -20.f), 2.f);
        out[(size_t)N_*8 + (size_t)node*8 + (p - 8)] = v;
      }
    }
  }
}

extern "C" void kernel_launch(void* const* d_in, const int* in_sizes, int n_in,
                              void* d_out, int out_size, void* d_ws, size_t ws_size,
                              hipStream_t stream)
{
  float* out = (float*)d_out;

  float code = 0.0f;
  if      (n_in != 21)                 code = 1.0e6f;
  else if (in_sizes[0]  != 3200000)    code = 2.0e6f;
  else if (in_sizes[1]  != 3200000)    code = 3.0e6f;
  else if (in_sizes[2]  != 1600000)    code = 4.0e6f;
  else if (in_sizes[3]  != 50000)      code = 5.0e6f;
  else if (in_sizes[4]  != 16384)      code = 6.0e6f;
  else if (in_sizes[13] != 36864)      code = 7.0e6f;
  else if (in_sizes[15] != 65536)      code = 8.0e6f;
  else if (in_sizes[17] != 2048)       code = 9.0e6f;
  else if (out_size     != 800000)     code = 1.0e7f;
  else if (ws_size      < WS_NEED)     code = 1.1e7f;
  if (code != 0.0f) {
    k_code<<<1, 64, 0, stream>>>(out, code);
    return;
  }

  const float* state = (const float*)d_in[0];
  const float* xn    = (const float*)d_in[1];
  const int*   ei    = (const int*)d_in[2];
  const int*   mo    = (const int*)d_in[3];
  const float* w1a   = (const float*)d_in[4];
  const float* b1a   = (const float*)d_in[5];
  const float* w1b   = (const float*)d_in[6];
  const float* b1b   = (const float*)d_in[7];
  const float* w2a   = (const float*)d_in[8];
  const float* b2a   = (const float*)d_in[9];
  const float* w2b   = (const float*)d_in[10];
  const float* b2b   = (const float*)d_in[11];
  const float* emb   = (const float*)d_in[12];
  const float* w1    = (const float*)d_in[13];
  const float* b1    = (const float*)d_in[14];
  const float* w2    = (const float*)d_in[15];
  const float* b2    = (const float*)d_in[16];
  const float* wm    = (const float*)d_in[17];
  const float* bm    = (const float*)d_in[18];
  const float* wsw   = (const float*)d_in[19];
  const float* bs    = (const float*)d_in[20];

  char* ws = (char*)d_ws;
  ushort_t* XB   = (ushort_t*)(ws + OFF_XB);
  int*      SRC  = (int*)(ws + OFF_SRC);
  int*      DST  = (int*)(ws + OFF_DST);
  ushort_t* H    = (ushort_t*)(ws + OFF_H);
  int*      ESRC = (int*)(ws + OFF_ESRC);
  int*      CUR  = (int*)(ws + OFF_CUR);
  ushort_t* G    = (ushort_t*)(ws + OFF_G);
  int*      OFFA = (int*)(ws + OFF_OFFA);
  int*      MODE = (int*)(ws + OFF_MODE);
  ushort_t* WTH  = (ushort_t*)(ws + OFF_WTH);
  ushort_t* E16  = (ushort_t*)(ws + OFF_E16);
  int*      FLG  = (int*)(ws + OFF_FLAG);
  int*      BS   = (int*)(ws + OFF_BS);
  ushort_t* Y1   = (ushort_t*)(ws + OFF_Y1);
  ushort_t* Y2   = (ushort_t*)(ws + OFF_Y2);

  hipMemsetAsync(CUR, 0, (size_t)N_ * 4, stream);
  k_detect <<<1,    256, 0, stream>>>(ei, mo, FLG);
  k_cvt    <<<1600, 256, 0, stream>>>(ei, mo, FLG, SRC, DST, MODE, CUR);
  k_scanA  <<<SB,   256, 0, stream>>>(CUR, BS);
  k_scanB  <<<1,    256, 0, stream>>>(BS, OFFA);
  k_scanC  <<<SB,   256, 0, stream>>>(BS, CUR, OFFA);
  k_scatter<<<1600, 256, 0, stream>>>(SRC, DST, CUR, ESRC);
  k_prep   <<<12517,256, 0, stream>>>(xn, wm, wsw, emb, XB, WTH, E16);
  k_gnn1   <<<NB,   256, 0, stream>>>(XB, ESRC, OFFA, w1a, b1a, w1b, b1b, H);
  k_gnn2   <<<NB,   256, 0, stream>>>(H, ESRC, OFFA, w2a, b2a, w2b, b2b, G);
  k_mlp1   <<<256,  256, 0, stream>>>(state, G, E16, MODE, b1, w1, Y1);
  k_mlp2   <<<256,  256, 0, stream>>>(Y1, w2, b2, Y2);
  k_heads  <<<128,  256, 0, stream>>>(Y2, WTH, bm, bs, out);
}